// Round 1
// baseline (717.849 us; speedup 1.0000x reference)
//
#include <hip/hip_runtime.h>
#include <hip/hip_bf16.h>
#include <math.h>

// Problem constants: E=200000 edges, D=128, H=4 heads, N=50000 targets.
// seg = edge_index[1] (second row). Only edge_source_emb feeds messages.

#define DIM 128
#define NHEAD 4
#define TM 32   // nodes per block in k5

// ---------------- K0: init — zero counts, permute W2, fold a-vectors ----------------
__global__ __launch_bounds__(256)
void k0_init(const float* __restrict__ Wsrc, const float* __restrict__ Wdst,
             const float* __restrict__ att_src, const float* __restrict__ att_dst,
             int* __restrict__ counts, float* __restrict__ a_src,
             float* __restrict__ a_dst, float* __restrict__ W2, int N)
{
    int zb = (N + 1 + 255) >> 8;
    int b = blockIdx.x, t = threadIdx.x;
    if (b < zb) {
        int i = (b << 8) + t;
        if (i <= N) counts[i] = 0;
    } else if (b < zb + 256) {
        // W2[(h*128+k)*128 + d] = Wsrc[k*512 + h*128 + d]
        int i = ((b - zb) << 8) + t;        // 0..65535
        int d = i & 127, j = i >> 7;        // j = h*128+k
        int h = j >> 7, k = j & 127;
        W2[i] = Wsrc[k * 512 + h * 128 + d];
    } else {
        int bb = b - zb - 256;              // 0..3 : 0,1 -> a_src ; 2,3 -> a_dst
        int p = ((bb & 1) << 8) + t;        // 0..511 (k,h) pair
        int k = p >> 2, h = p & 3;
        const float* W  = (bb < 2) ? Wsrc : Wdst;
        const float* at = (bb < 2) ? att_src : att_dst;
        float* outv     = (bb < 2) ? a_src : a_dst;
        float acc = 0.f;
        for (int d = 0; d < DIM; ++d)
            acc += W[k * 512 + h * 128 + d] * at[h * 128 + d];
        outv[k * 4 + h] = acc;              // layout [k][h], float4 per k
    }
}

// ---------------- K1: per-edge attention logits (wave per edge) ----------------
__global__ __launch_bounds__(256)
void k1_alpha(const float* __restrict__ src, const float* __restrict__ dst,
              const float* __restrict__ a_src, const float* __restrict__ a_dst,
              float* __restrict__ alpha, int E)
{
    int lane = threadIdx.x & 63;
    int wid  = (blockIdx.x * 256 + threadIdx.x) >> 6;
    int nw   = (gridDim.x * 256) >> 6;
    const float4* as4 = (const float4*)a_src;
    const float4* ad4 = (const float4*)a_dst;
    // per-lane slice of the folded attention vectors (k = 2*lane, 2*lane+1)
    float4 as0 = as4[2 * lane], as1 = as4[2 * lane + 1];
    float4 ad0 = ad4[2 * lane], ad1 = ad4[2 * lane + 1];
    const float2* s2 = (const float2*)src;
    const float2* t2 = (const float2*)dst;
    for (int e = wid; e < E; e += nw) {
        float2 s = s2[e * 64 + lane];
        float2 u = t2[e * 64 + lane];
        float px = s.x*as0.x + s.y*as1.x + u.x*ad0.x + u.y*ad1.x;
        float py = s.x*as0.y + s.y*as1.y + u.x*ad0.y + u.y*ad1.y;
        float pz = s.x*as0.z + s.y*as1.z + u.x*ad0.z + u.y*ad1.z;
        float pw = s.x*as0.w + s.y*as1.w + u.x*ad0.w + u.y*ad1.w;
        for (int off = 32; off; off >>= 1) {
            px += __shfl_down(px, off, 64);
            py += __shfl_down(py, off, 64);
            pz += __shfl_down(pz, off, 64);
            pw += __shfl_down(pw, off, 64);
        }
        if (lane == 0) {
            float4 r;   // leaky_relu(x) = max(x, 0.2x)
            r.x = fmaxf(px, 0.2f * px);
            r.y = fmaxf(py, 0.2f * py);
            r.z = fmaxf(pz, 0.2f * pz);
            r.w = fmaxf(pw, 0.2f * pw);
            ((float4*)alpha)[e] = r;
        }
    }
}

// ---------------- K2: histogram ----------------
__global__ __launch_bounds__(256)
void k2_hist(const int* __restrict__ seg, int* __restrict__ counts, int E)
{
    int i = blockIdx.x * 256 + threadIdx.x;
    if (i < E) atomicAdd(&counts[seg[i]], 1);
}

// ---------------- K3: single-block exclusive scan -> offsets (+cursor copy) ----------------
__global__ __launch_bounds__(1024)
void k3_scan(int* __restrict__ counts, int* __restrict__ cursor, int N)
{
    __shared__ int ls[1024];
    int t = threadIdx.x;
    int C = (N + 1023) >> 10;
    int lo = t * C;
    int hi = lo + C; if (hi > N) hi = N;
    int s = 0;
    for (int i = lo; i < hi; ++i) s += counts[i];
    ls[t] = s;
    for (int off = 1; off < 1024; off <<= 1) {
        __syncthreads();
        int v = (t >= off) ? ls[t - off] : 0;
        __syncthreads();
        ls[t] += v;
    }
    __syncthreads();
    int run = ls[t] - s;    // exclusive prefix of this chunk
    for (int i = lo; i < hi; ++i) {
        int c = counts[i];
        counts[i] = run;
        cursor[i] = run;
        run += c;
    }
    if (t == 1023) counts[N] = ls[1023];
}

// ---------------- K4: scatter edge ids into CSR ----------------
__global__ __launch_bounds__(256)
void k4_scatter(const int* __restrict__ seg, int* __restrict__ cursor,
                int* __restrict__ elist, int E)
{
    int i = blockIdx.x * 256 + threadIdx.x;
    if (i < E) {
        int pos = atomicAdd(&cursor[seg[i]], 1);
        elist[pos] = i;
    }
}

// ---------------- K5: per-node softmax + aggregate G (LDS) + GEMM vs W2 ----------------
__global__ __launch_bounds__(256)
void k5_agg(const float* __restrict__ src, const float* __restrict__ alpha,
            const int* __restrict__ offsets, const int* __restrict__ elist,
            const float* __restrict__ W2, float* __restrict__ out, int N)
{
    __shared__ float Gs[TM][512];   // 64 KB
    __shared__ float Ws[32][128];   // 16 KB
    int t = threadIdx.x, lane = t & 63, wv = t >> 6;
    int nbase = blockIdx.x * TM;

    for (int i = t; i < TM * 512; i += 256) ((float*)Gs)[i] = 0.f;
    __syncthreads();

    const float4* a4 = (const float4*)alpha;
    // phase 1: each wave owns 8 consecutive nodes
    for (int j = 0; j < 8; ++j) {
        int nloc = wv * 8 + j;
        int n = nbase + nloc;
        if (n >= N) continue;
        int off = offsets[n];
        int deg = offsets[n + 1] - off;
        if (deg == 0) continue;
        float m0 = -1e30f, m1 = -1e30f, m2 = -1e30f, m3 = -1e30f;
        for (int i = 0; i < deg; ++i) {
            float4 a = a4[elist[off + i]];
            m0 = fmaxf(m0, a.x); m1 = fmaxf(m1, a.y);
            m2 = fmaxf(m2, a.z); m3 = fmaxf(m3, a.w);
        }
        float s0 = 0.f, s1 = 0.f, s2 = 0.f, s3 = 0.f;
        for (int i = 0; i < deg; ++i) {
            float4 a = a4[elist[off + i]];
            s0 += __expf(a.x - m0); s1 += __expf(a.y - m1);
            s2 += __expf(a.z - m2); s3 += __expf(a.w - m3);
        }
        float r0 = 1.f / (s0 + 1e-16f), r1 = 1.f / (s1 + 1e-16f);
        float r2 = 1.f / (s2 + 1e-16f), r3 = 1.f / (s3 + 1e-16f);
        float a00=0,a01=0,a10=0,a11=0,a20=0,a21=0,a30=0,a31=0;
        for (int i = 0; i < deg; ++i) {
            int e = elist[off + i];
            float4 a = a4[e];
            float w0 = __expf(a.x - m0) * r0;
            float w1 = __expf(a.y - m1) * r1;
            float w2 = __expf(a.z - m2) * r2;
            float w3 = __expf(a.w - m3) * r3;
            float e0 = src[e * DIM + lane];
            float e1 = src[e * DIM + 64 + lane];
            a00 += w0 * e0; a01 += w0 * e1;
            a10 += w1 * e0; a11 += w1 * e1;
            a20 += w2 * e0; a21 += w2 * e1;
            a30 += w3 * e0; a31 += w3 * e1;
        }
        Gs[nloc][0*128 + lane] = a00; Gs[nloc][0*128 + 64 + lane] = a01;
        Gs[nloc][1*128 + lane] = a10; Gs[nloc][1*128 + 64 + lane] = a11;
        Gs[nloc][2*128 + lane] = a20; Gs[nloc][2*128 + 64 + lane] = a21;
        Gs[nloc][3*128 + lane] = a30; Gs[nloc][3*128 + 64 + lane] = a31;
    }

    // phase 2: out[nbase..nbase+31][0..127] = (1/H) * Gs @ W2
    float acc[8][2];
    #pragma unroll
    for (int j = 0; j < 8; ++j) { acc[j][0] = 0.f; acc[j][1] = 0.f; }
    for (int kc = 0; kc < 512; kc += 32) {
        __syncthreads();
        for (int i = t; i < 32 * 128; i += 256) {
            int r = i >> 7, d = i & 127;
            Ws[r][d] = W2[(kc + r) * 128 + d];
        }
        __syncthreads();
        for (int k = 0; k < 32; ++k) {
            float w0 = Ws[k][lane], w1 = Ws[k][64 + lane];
            #pragma unroll
            for (int j = 0; j < 8; ++j) {
                float g = Gs[wv * 8 + j][kc + k];
                acc[j][0] += g * w0;
                acc[j][1] += g * w1;
            }
        }
    }
    for (int j = 0; j < 8; ++j) {
        int n = nbase + wv * 8 + j;
        if (n < N) {
            out[n * DIM + lane]      = 0.25f * acc[j][0];
            out[n * DIM + 64 + lane] = 0.25f * acc[j][1];
        }
    }
}

extern "C" void kernel_launch(void* const* d_in, const int* in_sizes, int n_in,
                              void* d_out, int out_size, void* d_ws, size_t ws_size,
                              hipStream_t stream)
{
    const float* src     = (const float*)d_in[0];
    const float* dst     = (const float*)d_in[1];
    const int*   eidx    = (const int*)d_in[2];
    const float* Wsrc    = (const float*)d_in[3];
    const float* Wdst    = (const float*)d_in[4];
    const float* att_src = (const float*)d_in[5];
    const float* att_dst = (const float*)d_in[6];

    int E = in_sizes[0] / DIM;          // 200000
    int N = out_size / DIM;             // 50000
    const int* seg = eidx + E;          // edge_index[1]

    char* ws = (char*)d_ws;
    size_t o = 0;
    auto alloc = [&](size_t bytes) { size_t r = o; o += (bytes + 255) & ~(size_t)255; return r; };
    int*   counts = (int*)  (ws + alloc((size_t)(N + 1) * 4)); // becomes offsets
    int*   cursor = (int*)  (ws + alloc((size_t)N * 4));
    int*   elist  = (int*)  (ws + alloc((size_t)E * 4));
    float* a_src  = (float*)(ws + alloc(512 * 4));
    float* a_dst  = (float*)(ws + alloc(512 * 4));
    float* W2     = (float*)(ws + alloc(65536 * 4));
    float* alpha  = (float*)(ws + alloc((size_t)E * NHEAD * 4));
    (void)ws_size; (void)n_in;

    int zb = (N + 1 + 255) >> 8;
    k0_init<<<zb + 256 + 4, 256, 0, stream>>>(Wsrc, Wdst, att_src, att_dst,
                                              counts, a_src, a_dst, W2, N);
    k1_alpha<<<1024, 256, 0, stream>>>(src, dst, a_src, a_dst, alpha, E);
    k2_hist<<<(E + 255) / 256, 256, 0, stream>>>(seg, counts, E);
    k3_scan<<<1, 1024, 0, stream>>>(counts, cursor, N);
    k4_scatter<<<(E + 255) / 256, 256, 0, stream>>>(seg, cursor, elist, E);
    k5_agg<<<(N + TM - 1) / TM, 256, 0, stream>>>(src, alpha, counts, elist,
                                                  W2, (float*)d_out, N);
}